// Round 1
// baseline (2390.489 us; speedup 1.0000x reference)
//
#include <hip/hip_runtime.h>

#define B_SZ 2048
#define N_SZ 64
#define H_SZ 256

typedef __bf16 bf16_t;
typedef bf16_t bf16x8 __attribute__((ext_vector_type(8)));
typedef bf16_t bf16x4 __attribute__((ext_vector_type(4)));
typedef float  f32x4  __attribute__((ext_vector_type(4)));

// ---- LDS layout (bf16-element strides; all row strides are multiples of 8 bf16
// = 16B so ds_read_b128 stays aligned; +8 pad spreads bank groups uniformly) ----
#define SH  264   // lds h:      64 x 256  (+8 pad)   -> 33792 B
#define SA  136   // lds A:      64 x 128  (+8 pad)   -> 17408 B
#define SXT 72    // lds X^T:   256 x  64  (+8 pad)   -> 36864 B
#define SI  520   // lds inputs: 64 x 512  (+8 pad)   -> 66560 B

#define LH_OFF    0
#define LA_OFF    33792
#define LXT_OFF   51200
#define LIN_OFF   88064
#define LSTAR_OFF 154624   // 256 f32
#define LRED_OFF  155648   // 512 f32
#define LSIM_OFF  157696   // 64 f32
#define LMASK_OFF 157952   // 64 f32
#define LDS_BYTES 158208   // < 163840 (160 KiB) -> 1 WG/CU

// swizzled-weight regions in d_ws (bf16 elements)
#define SWZ_WCAT 0                    // [W_in; W_out]: 512 rows x K=256 (KB=8)
#define SWZ_WIH  131072               // w_ih: 768 rows x K=512 (KB=16)
#define SWZ_WHH  (131072 + 393216)    // w_hh: 768 rows x K=256 (KB=8)

__device__ __forceinline__ f32x4 mfma16(bf16x8 a, bf16x8 b, f32x4 c) {
  return __builtin_amdgcn_mfma_f32_16x16x32_bf16(a, b, c, 0, 0, 0);
}
__device__ __forceinline__ float sigm_(float x) { return 1.0f / (1.0f + __expf(-x)); }
__device__ __forceinline__ float tanh_(float x) { return 2.0f / (1.0f + __expf(-2.0f * x)) - 1.0f; }

// Pre-swizzle weights into MFMA B-fragment order:
// element (n,k) -> idx = ((nt*KB + kb)*64 + lane)*8 + j with
// n = nt*16 + (lane&15), k = kb*32 + (lane>>4)*8 + j.
// A wave's B-fragment load is then one coalesced 16B/lane global load.
__global__ void swz_kernel(const float* __restrict__ W_in, const float* __restrict__ W_out,
                           const float* __restrict__ w_ih, const float* __restrict__ w_hh,
                           bf16_t* __restrict__ ws) {
  const int f = blockIdx.x * blockDim.x + threadIdx.x;
  const float* src;
  bf16_t* dst;
  if (f < 16384) {                       // Wcat = [W_in; W_out] (512 x 256), KB=8
    const int fl = f, l = fl & 63, rem = fl >> 6, kb = rem & 7, nt = rem >> 3;
    const int n = nt * 16 + (l & 15), k = kb * 32 + ((l >> 4) << 3);
    src = (n < 256) ? (W_in + n * 256 + k) : (W_out + (n - 256) * 256 + k);
    dst = ws + SWZ_WCAT + (size_t)fl * 8;
  } else if (f < 65536) {                // w_ih (768 x 512), KB=16
    const int fl = f - 16384, l = fl & 63, rem = fl >> 6, kb = rem & 15, nt = rem >> 4;
    const int n = nt * 16 + (l & 15), k = kb * 32 + ((l >> 4) << 3);
    src = w_ih + n * 512 + k;
    dst = ws + SWZ_WIH + (size_t)fl * 8;
  } else {                               // w_hh (768 x 256), KB=8
    const int fl = f - 65536, l = fl & 63, rem = fl >> 6, kb = rem & 7, nt = rem >> 3;
    const int n = nt * 16 + (l & 15), k = kb * 32 + ((l >> 4) << 3);
    src = w_hh + n * 256 + k;
    dst = ws + SWZ_WHH + (size_t)fl * 8;
  }
  bf16x8 v;
  #pragma unroll
  for (int j = 0; j < 8; ++j) v[j] = (bf16_t)src[j];
  *(bf16x8*)dst = v;
}

// One workgroup per batch element; whole 2-step recurrence in LDS.
__launch_bounds__(512, 2)
__global__ void sgnn_main(
    const float* __restrict__ Aptr, const float* __restrict__ hid,
    const float* __restrict__ gmask,
    const float* __restrict__ b_ih, const float* __restrict__ b_hh,
    const float* __restrict__ b_iah, const float* __restrict__ b_oah,
    const float* __restrict__ b_in, const float* __restrict__ b_out,
    const bf16_t* __restrict__ swzWcat, const bf16_t* __restrict__ swzWih,
    const bf16_t* __restrict__ swzWhh,
    float* __restrict__ out_h, float* __restrict__ out_star) {
  extern __shared__ char lds[];
  bf16_t* lh   = (bf16_t*)(lds + LH_OFF);
  bf16_t* lA   = (bf16_t*)(lds + LA_OFF);
  bf16_t* lXT  = (bf16_t*)(lds + LXT_OFF);
  bf16_t* lin  = (bf16_t*)(lds + LIN_OFF);
  float* lstar = (float*)(lds + LSTAR_OFF);
  float* lred  = (float*)(lds + LRED_OFF);
  float* lsim  = (float*)(lds + LSIM_OFF);
  float* lmask = (float*)(lds + LMASK_OFF);

  const int b = blockIdx.x;
  const int t = threadIdx.x;
  const int w = t >> 6;           // wave id 0..7
  const int l = t & 63;           // lane
  const int quad = l >> 4, ln16 = l & 15;

  // ---- load h (bf16), A (bf16), mask ----
  {
    const int n = t >> 3, g = t & 7;
    const float* hsrc = hid + ((size_t)b * 64 + n) * 256;
    #pragma unroll
    for (int j = 0; j < 8; ++j) {
      const int c = 4 * (g + 8 * j);
      const float4 v = *(const float4*)(hsrc + c);
      bf16x4 bv = {(bf16_t)v.x, (bf16_t)v.y, (bf16_t)v.z, (bf16_t)v.w};
      *(bf16x4*)(lh + n * SH + c) = bv;
    }
    const float* asrc = Aptr + ((size_t)b * 64 + n) * 128;
    #pragma unroll
    for (int j = 0; j < 4; ++j) {
      const int c = 4 * (g + 8 * j);
      const float4 v = *(const float4*)(asrc + c);
      bf16x4 bv = {(bf16_t)v.x, (bf16_t)v.y, (bf16_t)v.z, (bf16_t)v.w};
      *(bf16x4*)(lA + n * SA + c) = bv;
    }
    if (t < 64) lmask[t] = gmask[(size_t)b * 64 + t];
  }
  __syncthreads();

  // ---- init star = sum_n h*mask / sum(mask) ----
  {
    float len = 0.f;
    #pragma unroll 1
    for (int n2 = 0; n2 < 64; ++n2) len += lmask[n2];
    const int c = t & 255, hf = t >> 8;
    float s = 0.f;
    #pragma unroll 1
    for (int n2 = hf * 32; n2 < hf * 32 + 32; ++n2)
      s += (float)lh[n2 * SH + c] * lmask[n2];
    lred[t] = s;
    __syncthreads();
    if (t < 256) lstar[t] = (lred[t] + lred[t + 256]) / len;
  }
  __syncthreads();

  for (int step = 0; step < 2; ++step) {
    // ================= Phase 1: X = h@W^T + b ; inputs_half = A_half@X + b =================
    #pragma unroll 1
    for (int half = 0; half < 2; ++half) {
      // --- GEMM X (64x256, K=256): wave -> ntiles {2w,2w+1}, all 4 mtiles ---
      f32x4 acc[2][4] = {};
      for (int kb = 0; kb < 8; ++kb) {
        bf16x8 af[4];
        #pragma unroll
        for (int mt = 0; mt < 4; ++mt)
          af[mt] = *(bf16x8*)(lh + (mt * 16 + ln16) * SH + kb * 32 + quad * 8);
        #pragma unroll
        for (int nt2 = 0; nt2 < 2; ++nt2) {
          const int nt = half * 16 + 2 * w + nt2;
          const bf16x8 bfr = *(const bf16x8*)(swzWcat + ((size_t)(nt * 8 + kb) * 64 + l) * 8);
          #pragma unroll
          for (int mt = 0; mt < 4; ++mt) acc[nt2][mt] = mfma16(af[mt], bfr, acc[nt2][mt]);
        }
      }
      __syncthreads();  // protect lXT (previous consumer done)
      {
        const float* bvec = half ? b_out : b_in;
        #pragma unroll
        for (int nt2 = 0; nt2 < 2; ++nt2) {
          const int c = (2 * w + nt2) * 16 + ln16;
          const float bb = bvec[c];
          #pragma unroll
          for (int mt = 0; mt < 4; ++mt) {
            const int m0 = mt * 16 + quad * 4;
            bf16x4 v = {(bf16_t)(acc[nt2][mt][0] + bb), (bf16_t)(acc[nt2][mt][1] + bb),
                        (bf16_t)(acc[nt2][mt][2] + bb), (bf16_t)(acc[nt2][mt][3] + bb)};
            *(bf16x4*)(lXT + c * SXT + m0) = v;   // store X transposed (B-frag friendly)
          }
        }
      }
      __syncthreads();
      // --- GEMM inputs_half = A_half @ X (64x256, K=64) ---
      f32x4 acc2[2][4] = {};
      for (int kb = 0; kb < 2; ++kb) {
        bf16x8 af[4];
        #pragma unroll
        for (int mt = 0; mt < 4; ++mt)
          af[mt] = *(bf16x8*)(lA + (mt * 16 + ln16) * SA + half * 64 + kb * 32 + quad * 8);
        #pragma unroll
        for (int nt2 = 0; nt2 < 2; ++nt2) {
          const int ct = 2 * w + nt2;
          const bf16x8 bfr = *(bf16x8*)(lXT + (ct * 16 + ln16) * SXT + kb * 32 + quad * 8);
          #pragma unroll
          for (int mt = 0; mt < 4; ++mt) acc2[nt2][mt] = mfma16(af[mt], bfr, acc2[nt2][mt]);
        }
      }
      {
        const float* bah = half ? b_oah : b_iah;
        #pragma unroll
        for (int nt2 = 0; nt2 < 2; ++nt2) {
          const int c = (2 * w + nt2) * 16 + ln16;
          const float bb = bah[c];
          #pragma unroll
          for (int mt = 0; mt < 4; ++mt) {
            const int m0 = mt * 16 + quad * 4;
            #pragma unroll
            for (int i = 0; i < 4; ++i)
              lin[(m0 + i) * SI + half * 256 + c] = (bf16_t)(acc2[nt2][mt][i] + bb);
          }
        }
      }
    }
    __syncthreads();   // inputs (64x512) complete

    // ================= Phase 2a: r,z gates (gi+gh fused accumulation) =================
    float rg[2][4][4], zg[2][4][4];
    {
      f32x4 accr[2][4] = {}, accz[2][4] = {};
      for (int kb = 0; kb < 16; ++kb) {     // gi part, K=512 from inputs
        bf16x8 af[4];
        #pragma unroll
        for (int mt = 0; mt < 4; ++mt)
          af[mt] = *(bf16x8*)(lin + (mt * 16 + ln16) * SI + kb * 32 + quad * 8);
        #pragma unroll
        for (int nt2 = 0; nt2 < 2; ++nt2) {
          const int ntc = 2 * w + nt2;
          const bf16x8 br = *(const bf16x8*)(swzWih + ((size_t)(ntc * 16 + kb) * 64 + l) * 8);
          const bf16x8 bz = *(const bf16x8*)(swzWih + ((size_t)((16 + ntc) * 16 + kb) * 64 + l) * 8);
          #pragma unroll
          for (int mt = 0; mt < 4; ++mt) {
            accr[nt2][mt] = mfma16(af[mt], br, accr[nt2][mt]);
            accz[nt2][mt] = mfma16(af[mt], bz, accz[nt2][mt]);
          }
        }
      }
      for (int kb = 0; kb < 8; ++kb) {      // gh part, K=256 from h
        bf16x8 af[4];
        #pragma unroll
        for (int mt = 0; mt < 4; ++mt)
          af[mt] = *(bf16x8*)(lh + (mt * 16 + ln16) * SH + kb * 32 + quad * 8);
        #pragma unroll
        for (int nt2 = 0; nt2 < 2; ++nt2) {
          const int ntc = 2 * w + nt2;
          const bf16x8 br = *(const bf16x8*)(swzWhh + ((size_t)(ntc * 8 + kb) * 64 + l) * 8);
          const bf16x8 bz = *(const bf16x8*)(swzWhh + ((size_t)((16 + ntc) * 8 + kb) * 64 + l) * 8);
          #pragma unroll
          for (int mt = 0; mt < 4; ++mt) {
            accr[nt2][mt] = mfma16(af[mt], br, accr[nt2][mt]);
            accz[nt2][mt] = mfma16(af[mt], bz, accz[nt2][mt]);
          }
        }
      }
      #pragma unroll
      for (int nt2 = 0; nt2 < 2; ++nt2) {
        const int c = (2 * w + nt2) * 16 + ln16;
        const float br_ = b_ih[c] + b_hh[c];
        const float bz_ = b_ih[256 + c] + b_hh[256 + c];
        #pragma unroll
        for (int mt = 0; mt < 4; ++mt)
          #pragma unroll
          for (int i = 0; i < 4; ++i) {
            rg[nt2][mt][i] = sigm_(accr[nt2][mt][i] + br_);
            zg[nt2][mt][i] = sigm_(accz[nt2][mt][i] + bz_);
          }
      }
    }

    // ================= Phase 2b: n gate + GRU update (in-place h) =================
    {
      f32x4 acci[2][4] = {}, acch[2][4] = {};
      for (int kb = 0; kb < 16; ++kb) {     // gi n-part
        bf16x8 af[4];
        #pragma unroll
        for (int mt = 0; mt < 4; ++mt)
          af[mt] = *(bf16x8*)(lin + (mt * 16 + ln16) * SI + kb * 32 + quad * 8);
        #pragma unroll
        for (int nt2 = 0; nt2 < 2; ++nt2) {
          const int ntc = 2 * w + nt2;
          const bf16x8 bn = *(const bf16x8*)(swzWih + ((size_t)((32 + ntc) * 16 + kb) * 64 + l) * 8);
          #pragma unroll
          for (int mt = 0; mt < 4; ++mt) acci[nt2][mt] = mfma16(af[mt], bn, acci[nt2][mt]);
        }
      }
      for (int kb = 0; kb < 8; ++kb) {      // gh n-part
        bf16x8 af[4];
        #pragma unroll
        for (int mt = 0; mt < 4; ++mt)
          af[mt] = *(bf16x8*)(lh + (mt * 16 + ln16) * SH + kb * 32 + quad * 8);
        #pragma unroll
        for (int nt2 = 0; nt2 < 2; ++nt2) {
          const int ntc = 2 * w + nt2;
          const bf16x8 bn = *(const bf16x8*)(swzWhh + ((size_t)((32 + ntc) * 8 + kb) * 64 + l) * 8);
          #pragma unroll
          for (int mt = 0; mt < 4; ++mt) acch[nt2][mt] = mfma16(af[mt], bn, acch[nt2][mt]);
        }
      }
      __syncthreads();   // all K-loop reads of lh done before in-place write
      #pragma unroll
      for (int nt2 = 0; nt2 < 2; ++nt2) {
        const int c = (2 * w + nt2) * 16 + ln16;
        const float bi_ = b_ih[512 + c];
        const float bh_ = b_hh[512 + c];
        #pragma unroll
        for (int mt = 0; mt < 4; ++mt) {
          const int m0 = mt * 16 + quad * 4;
          #pragma unroll
          for (int i = 0; i < 4; ++i) {
            const float nn = tanh_(acci[nt2][mt][i] + bi_ + rg[nt2][mt][i] * (acch[nt2][mt][i] + bh_));
            const float ho = (float)lh[(m0 + i) * SH + c];
            const float hn = nn + zg[nt2][mt][i] * (ho - nn);
            lh[(m0 + i) * SH + c] = (bf16_t)hn;   // own (row,col): no cross-lane hazard
          }
        }
      }
    }
    __syncthreads();

    // ================= Phase 3: attention mix + star update =================
    {
      const int n = t >> 3, g = t & 7;
      float hv[32];
      float dot = 0.f;
      #pragma unroll
      for (int j = 0; j < 8; ++j) {
        const int c = 4 * (g + 8 * j);
        const bf16x4 v = *(bf16x4*)(lh + n * SH + c);
        const float4 sv = *(const float4*)(lstar + c);
        hv[4 * j + 0] = (float)v[0]; hv[4 * j + 1] = (float)v[1];
        hv[4 * j + 2] = (float)v[2]; hv[4 * j + 3] = (float)v[3];
        dot += hv[4 * j + 0] * sv.x + hv[4 * j + 1] * sv.y +
               hv[4 * j + 2] * sv.z + hv[4 * j + 3] * sv.w;
      }
      dot += __shfl_xor(dot, 1); dot += __shfl_xor(dot, 2); dot += __shfl_xor(dot, 4);
      const float alpha = sigm_(dot * 0.0625f);      // inv_sqrt_h = 1/16
      float dot2 = 0.f;
      #pragma unroll
      for (int j = 0; j < 8; ++j) {
        const int c = 4 * (g + 8 * j);
        const float4 sv = *(const float4*)(lstar + c);
        float m0 = (1.f - alpha) * hv[4 * j + 0] + alpha * sv.x;
        float m1 = (1.f - alpha) * hv[4 * j + 1] + alpha * sv.y;
        float m2 = (1.f - alpha) * hv[4 * j + 2] + alpha * sv.z;
        float m3 = (1.f - alpha) * hv[4 * j + 3] + alpha * sv.w;
        hv[4 * j + 0] = m0; hv[4 * j + 1] = m1; hv[4 * j + 2] = m2; hv[4 * j + 3] = m3;
        dot2 += m0 * sv.x + m1 * sv.y + m2 * sv.z + m3 * sv.w;
      }
      dot2 += __shfl_xor(dot2, 1); dot2 += __shfl_xor(dot2, 2); dot2 += __shfl_xor(dot2, 4);
      #pragma unroll
      for (int j = 0; j < 8; ++j) {
        const int c = 4 * (g + 8 * j);
        bf16x4 bv = {(bf16_t)hv[4 * j + 0], (bf16_t)hv[4 * j + 1],
                     (bf16_t)hv[4 * j + 2], (bf16_t)hv[4 * j + 3]};
        *(bf16x4*)(lh + n * SH + c) = bv;
        if (step == 1) {
          float4 ov;
          ov.x = hv[4 * j + 0]; ov.y = hv[4 * j + 1];
          ov.z = hv[4 * j + 2]; ov.w = hv[4 * j + 3];
          *(float4*)(out_h + ((size_t)b * 64 + n) * 256 + c) = ov;
        }
      }
      const float e = __expf(dot2) * lmask[n];
      if (g == 0) lsim[n] = e;
    }
    __syncthreads();
    {
      float den = 1e-24f;
      #pragma unroll 1
      for (int n2 = 0; n2 < 64; ++n2) den += lsim[n2];
      const int c = t & 255, hf = t >> 8;
      float s = 0.f;
      #pragma unroll 1
      for (int n2 = hf * 32; n2 < hf * 32 + 32; ++n2)
        s += lsim[n2] * (float)lh[n2 * SH + c];
      lred[t] = s;
      __syncthreads();
      if (t < 256) {
        const float sn = (lred[t] + lred[t + 256]) / den;
        lstar[t] = sn;
        if (step == 1) out_star[(size_t)b * 256 + t] = sn;
      }
      __syncthreads();
    }
  }
}

extern "C" void kernel_launch(void* const* d_in, const int* in_sizes, int n_in,
                              void* d_out, int out_size, void* d_ws, size_t ws_size,
                              hipStream_t stream) {
  const float* A     = (const float*)d_in[0];
  const float* hid   = (const float*)d_in[1];
  const float* gmask = (const float*)d_in[2];
  const float* w_ih  = (const float*)d_in[3];
  const float* w_hh  = (const float*)d_in[4];
  const float* b_ih  = (const float*)d_in[5];
  const float* b_hh  = (const float*)d_in[6];
  const float* b_iah = (const float*)d_in[7];
  const float* b_oah = (const float*)d_in[8];
  const float* W_in  = (const float*)d_in[9];
  const float* b_in  = (const float*)d_in[10];
  const float* W_out = (const float*)d_in[11];
  const float* b_out = (const float*)d_in[12];
  float* out = (float*)d_out;
  bf16_t* swz = (bf16_t*)d_ws;

  (void)hipFuncSetAttribute((const void*)sgnn_main,
                            hipFuncAttributeMaxDynamicSharedMemorySize, LDS_BYTES);

  swz_kernel<<<352, 256, 0, stream>>>(W_in, W_out, w_ih, w_hh, swz);
  sgnn_main<<<B_SZ, 512, LDS_BYTES, stream>>>(
      A, hid, gmask, b_ih, b_hh, b_iah, b_oah, b_in, b_out,
      swz + SWZ_WCAT, swz + SWZ_WIH, swz + SWZ_WHH,
      out, out + (size_t)B_SZ * N_SZ * H_SZ);
}